// Round 1
// baseline (135.887 us; speedup 1.0000x reference)
//
#include <hip/hip_runtime.h>

#define BB 16
#define NN 300
#define PP 100
#define LL 32
#define HH 768
#define WW 768

__device__ __forceinline__ float relu_f(float x) { return fmaxf(x, 0.f); }

// ---------------------------------------------------------------------------
// K1: per-row inclusive scan of d[b,y,x] = seg[b,2,y,x] - seg[b,1,y,x]
// one block per row (b*H+y), 768 threads, f64 Hillis-Steele in LDS
// ---------------------------------------------------------------------------
__global__ void k_rowscan(const float* __restrict__ seg, float* __restrict__ out) {
    int row = blockIdx.x;            // b*HH + y
    int b = row / HH;
    int t = threadIdx.x;             // 0..767
    const float* s1 = seg + ((size_t)(b * 3 + 1) * HH * WW) + (size_t)(row % HH) * WW;
    const float* s2 = seg + ((size_t)(b * 3 + 2) * HH * WW) + (size_t)(row % HH) * WW;

    __shared__ double buf0[WW];
    __shared__ double buf1[WW];
    buf0[t] = (double)s2[t] - (double)s1[t];
    __syncthreads();

    double* src = buf0;
    double* dst = buf1;
    for (int off = 1; off < WW; off <<= 1) {
        double v = src[t];
        if (t >= off) v += src[t - off];
        dst[t] = v;
        __syncthreads();
        double* tmp = src; src = dst; dst = tmp;
    }
    out[(size_t)row * WW + t] = (float)src[t];
}

// ---------------------------------------------------------------------------
// K2: column-wise running sum over y (in place), f64 accumulator per column.
// one thread per (b, x) column; grid = B*W/256 blocks of 256
// ---------------------------------------------------------------------------
__global__ void k_colscan(float* __restrict__ data) {
    int gid = blockIdx.x * blockDim.x + threadIdx.x;   // 0 .. B*W-1
    int b = gid / WW;
    int x = gid % WW;
    float* p = data + (size_t)b * HH * WW + x;
    double acc = 0.0;
    for (int y = 0; y < HH; ++y) {
        acc += (double)p[(size_t)y * WW];
        p[(size_t)y * WW] = (float)acc;
    }
}

// ---------------------------------------------------------------------------
// K3: per-detection term. Computes det_conf (softmax max), caches it,
// does 4-corner integral lookups, block-reduces partial sums.
// ---------------------------------------------------------------------------
__global__ void k_det(const float* __restrict__ det_boxes,
                      const float* __restrict__ logits,
                      const float* __restrict__ integ,
                      float* __restrict__ det_conf,
                      float* __restrict__ detPart) {
    const float CONF_TH = 0.3f;
    int idx = blockIdx.x * blockDim.x + threadIdx.x;
    float contrib = 0.f;
    if (idx < BB * NN) {
        int b = idx / NN;
        const float* lg = logits + (size_t)idx * 7;
        float m = lg[0];
        #pragma unroll
        for (int i = 1; i < 7; ++i) m = fmaxf(m, lg[i]);
        float s = 0.f;
        #pragma unroll
        for (int i = 0; i < 7; ++i) s += expf(lg[i] - m);
        float conf = 1.f / s;
        det_conf[idx] = conf;

        const float* bx = det_boxes + (size_t)idx * 4;
        float cx = bx[0], cy = bx[1], w = bx[2], h = bx[3];
        float xf1 = (cx - w * 0.5f) * (float)WW;
        float yf1 = (cy - h * 0.5f) * (float)HH;
        float xf2 = (cx + w * 0.5f) * (float)WW;
        float yf2 = (cy + h * 0.5f) * (float)HH;
        int x1 = (int)floorf(xf1), y1 = (int)floorf(yf1);
        int x2 = (int)floorf(xf2), y2 = (int)floorf(yf2);
        x1 = min(max(x1, 0), WW - 1); y1 = min(max(y1, 0), HH - 1);
        x2 = min(max(x2, 0), WW - 1); y2 = min(max(y2, 0), HH - 1);

        if (conf >= CONF_TH && x2 > x1 && y2 > y1) {
            const float* I = integ + (size_t)b * HH * WW;
            // padded lookup: (y==0 || x==0) -> 0 else I[y-1][x-1]
            float i22 = (y2 == 0 || x2 == 0) ? 0.f : I[(size_t)(y2 - 1) * WW + (x2 - 1)];
            float i12 = (y1 == 0 || x2 == 0) ? 0.f : I[(size_t)(y1 - 1) * WW + (x2 - 1)];
            float i21 = (y2 == 0 || x1 == 0) ? 0.f : I[(size_t)(y2 - 1) * WW + (x1 - 1)];
            float i11 = (y1 == 0 || x1 == 0) ? 0.f : I[(size_t)(y1 - 1) * WW + (x1 - 1)];
            float S = i22 - i12 - i21 + i11;
            float area = (float)((y2 - y1) * (x2 - x1));
            contrib = relu_f(S / area) * conf;
        }
    }
    __shared__ float red[256];
    red[threadIdx.x] = contrib;
    __syncthreads();
    for (int s = 128; s > 0; s >>= 1) {
        if (threadIdx.x < s) red[threadIdx.x] += red[threadIdx.x + s];
        __syncthreads();
    }
    if (threadIdx.x == 0) detPart[blockIdx.x] = red[0];
}

// ---------------------------------------------------------------------------
// K4: per-batch plate IoU term + OCR term. One block per batch, 128 threads.
// ---------------------------------------------------------------------------
__global__ void k_plate_ocr(const float* __restrict__ det_boxes,
                            const float* __restrict__ det_conf,
                            const float* __restrict__ plate_boxes,
                            const float* __restrict__ plate_conf,
                            const float* __restrict__ ocr,
                            float* __restrict__ platePart,
                            float* __restrict__ plateCnt,
                            float* __restrict__ ocrPart) {
    const float CONF_TH = 0.3f;
    const float MIN_IOU = 0.5f;
    const float OCR_TH  = 0.7f;
    int b = blockIdx.x;
    int t = threadIdx.x;

    __shared__ float vx1[NN], vy1[NN], vx2[NN], vy2[NN], va[NN], vcf[NN];
    __shared__ int anyv;
    __shared__ float redf[128];
    __shared__ int   redi[128];

    if (t == 0) anyv = 0;
    __syncthreads();

    for (int j = t; j < NN; j += blockDim.x) {
        const float* bx = det_boxes + ((size_t)b * NN + j) * 4;
        float cx = bx[0], cy = bx[1], w = bx[2], h = bx[3];
        float x1 = cx - w * 0.5f, y1 = cy - h * 0.5f;
        float x2 = cx + w * 0.5f, y2 = cy + h * 0.5f;
        vx1[j] = x1; vy1[j] = y1; vx2[j] = x2; vy2[j] = y2;
        va[j] = (x2 - x1) * (y2 - y1);
        float c = det_conf[b * NN + j];
        vcf[j] = c;
        if (c > CONF_TH) atomicOr(&anyv, 1);
    }
    __syncthreads();

    float term = 0.f;
    int   pv   = 0;
    float pcf  = -1.f;
    if (t < PP) {
        const float* bx = plate_boxes + ((size_t)b * PP + t) * 4;
        float cx = bx[0], cy = bx[1], w = bx[2], h = bx[3];
        float px1 = cx - w * 0.5f, py1 = cy - h * 0.5f;
        float px2 = cx + w * 0.5f, py2 = cy + h * 0.5f;
        float a1 = (px2 - px1) * (py2 - py1);
        pcf = plate_conf[b * PP + t];
        pv = (pcf > CONF_TH) ? 1 : 0;
        float max_iou = -1.f;
        for (int j = 0; j < NN; ++j) {
            if (vcf[j] > CONF_TH) {
                float ltx = fmaxf(px1, vx1[j]);
                float lty = fmaxf(py1, vy1[j]);
                float rbx = fminf(px2, vx2[j]);
                float rby = fminf(py2, vy2[j]);
                float iw = fmaxf(rbx - ltx, 0.f);
                float ih = fmaxf(rby - lty, 0.f);
                float inter = iw * ih;
                float uni = a1 + va[j] - inter;
                float iou = inter / (uni + 1e-8f);
                max_iou = fmaxf(max_iou, iou);
            }
        }
        if (pv) term = relu_f(MIN_IOU - max_iou) * pcf;
    }

    // reduce term-sum and valid count
    redf[t] = term; redi[t] = pv;
    __syncthreads();
    for (int s = 64; s > 0; s >>= 1) {
        if (t < s) { redf[t] += redf[t + s]; redi[t] += redi[t + s]; }
        __syncthreads();
    }
    float termsum = redf[0];
    int   cnt     = redi[0];
    __syncthreads();

    // avg_ocr = mean over L of (max over 37)
    float osum = 0.f;
    if (t < LL) {
        const float* op = ocr + ((size_t)b * LL + t) * 37;
        float m = op[0];
        #pragma unroll
        for (int i = 1; i < 37; ++i) m = fmaxf(m, op[i]);
        osum = m;
    }
    redf[t] = osum;
    __syncthreads();
    for (int s = 64; s > 0; s >>= 1) {
        if (t < s) redf[t] += redf[t + s];
        __syncthreads();
    }
    float avg_ocr = redf[0] / (float)LL;
    __syncthreads();

    // max_plate = max over all P of plate_conf
    redf[t] = (t < PP) ? pcf : -1e30f;
    __syncthreads();
    for (int s = 64; s > 0; s >>= 1) {
        if (t < s) redf[t] = fmaxf(redf[t], redf[t + s]);
        __syncthreads();
    }
    float max_plate = redf[0];

    if (t == 0) {
        platePart[b] = (cnt > 0 && anyv) ? termsum : 0.f;
        plateCnt[b]  = (float)cnt;
        ocrPart[b]   = (avg_ocr > OCR_TH) ? relu_f(avg_ocr - max_plate) : 0.f;
    }
}

// ---------------------------------------------------------------------------
// K5: final deterministic combine (single thread; ~70 adds)
// ---------------------------------------------------------------------------
__global__ void k_final(const float* __restrict__ detPart, int nDet,
                        const float* __restrict__ platePart,
                        const float* __restrict__ plateCnt,
                        const float* __restrict__ ocrPart,
                        float* __restrict__ out) {
    if (threadIdx.x == 0 && blockIdx.x == 0) {
        double ds = 0.0;
        for (int i = 0; i < nDet; ++i) ds += (double)detPart[i];
        double ps = 0.0, cnt = 0.0, os = 0.0;
        for (int b = 0; b < BB; ++b) {
            ps  += (double)platePart[b];
            cnt += (double)plateCnt[b];
            os  += (double)ocrPart[b];
        }
        float det_seg   = (float)ds / (float)(BB * NN);
        float plate_det = (float)ps / fmaxf((float)cnt, 1.f);
        float ocr_plate = (float)os / (float)BB;
        out[0] = 0.1f * det_seg + 0.1f * plate_det + 0.1f * ocr_plate;
    }
}

extern "C" void kernel_launch(void* const* d_in, const int* in_sizes, int n_in,
                              void* d_out, int out_size, void* d_ws, size_t ws_size,
                              hipStream_t stream) {
    const float* det_boxes   = (const float*)d_in[0];
    const float* det_logits  = (const float*)d_in[1];
    const float* seg_masks   = (const float*)d_in[2];
    const float* plate_boxes = (const float*)d_in[3];
    const float* plate_conf  = (const float*)d_in[4];
    const float* ocr_probs   = (const float*)d_in[5];
    float* out = (float*)d_out;

    // workspace layout (floats)
    float* integral  = (float*)d_ws;                  // B*H*W
    float* det_conf  = integral + (size_t)BB * HH * WW;  // B*N
    float* detPart   = det_conf + BB * NN;            // up to 32
    float* platePart = detPart + 32;                  // 16
    float* plateCnt  = platePart + BB;                // 16
    float* ocrPart   = plateCnt + BB;                 // 16

    const int nDetBlocks = (BB * NN + 255) / 256;     // 19

    k_rowscan<<<BB * HH, WW, 0, stream>>>(seg_masks, integral);
    k_colscan<<<(BB * WW) / 256, 256, 0, stream>>>(integral);
    k_det<<<nDetBlocks, 256, 0, stream>>>(det_boxes, det_logits, integral,
                                          det_conf, detPart);
    k_plate_ocr<<<BB, 128, 0, stream>>>(det_boxes, det_conf, plate_boxes,
                                        plate_conf, ocr_probs,
                                        platePart, plateCnt, ocrPart);
    k_final<<<1, 64, 0, stream>>>(detPart, nDetBlocks, platePart, plateCnt,
                                  ocrPart, out);
}

// Round 2
// 89.144 us; speedup vs baseline: 1.5244x; 1.5244x over previous
//
#include <hip/hip_runtime.h>

#define BB 16
#define NN 300
#define PP 100
#define LL 32
#define HH 768
#define WW 768
#define ROWS 16   // rows per stripe in k_scan_t

__device__ __forceinline__ float relu_f(float x) { return fmaxf(x, 0.f); }

// ---------------------------------------------------------------------------
// K1: per-row inclusive prefix sums of d[b,y,x] = seg[b,2,y,x] - seg[b,1,y,x],
// written TRANSPOSED: RT[b][x][y].  Grid: BB * (HH/ROWS) = 768 blocks of 256.
// Wave-shuffle scans (no LDS scan iterations), LDS used as staging + transpose.
// ---------------------------------------------------------------------------
__global__ __launch_bounds__(256) void k_scan_t(const float* __restrict__ seg,
                                                float* __restrict__ RT) {
    const int blk    = blockIdx.x;
    const int b      = blk / (HH / ROWS);
    const int stripe = blk % (HH / ROWS);
    const int y0     = stripe * ROWS;
    const int t      = threadIdx.x;

    __shared__ float lds[ROWS * WW];   // 48 KB

    // stage d = seg[ch2] - seg[ch1] for ROWS rows, vectorized
    const float4* s1 = (const float4*)(seg + (size_t)(b * 3 + 1) * HH * WW + (size_t)y0 * WW);
    const float4* s2 = (const float4*)(seg + (size_t)(b * 3 + 2) * HH * WW + (size_t)y0 * WW);
    float4* dl = (float4*)lds;
    const int n4 = ROWS * WW / 4;      // 3072
    for (int i = t; i < n4; i += 256) {
        float4 a = s1[i], c = s2[i];
        float4 d;
        d.x = c.x - a.x; d.y = c.y - a.y; d.z = c.z - a.z; d.w = c.w - a.w;
        dl[i] = d;
    }
    __syncthreads();

    // row-wise inclusive scan: wave w handles rows w, w+4, w+8, w+12
    const int wave = t >> 6, lane = t & 63;
    for (int r = wave; r < ROWS; r += 4) {
        float* row = lds + r * WW;
        float carry = 0.f;
        for (int c = 0; c < WW / 64; ++c) {      // 12 chunks
            float v = row[c * 64 + lane];
            #pragma unroll
            for (int d = 1; d < 64; d <<= 1) {
                float o = __shfl_up(v, d, 64);
                if (lane >= d) v += o;
            }
            v += carry;
            row[c * 64 + lane] = v;
            carry = __shfl(v, 63, 64);
        }
    }
    __syncthreads();

    // transpose write: thread t covers x = t, t+256, t+512; 16 y's per x as float4s
    for (int xo = 0; xo < WW; xo += 256) {
        int x = xo + t;
        float* dst = RT + ((size_t)b * WW + x) * HH + y0;
        #pragma unroll
        for (int jj = 0; jj < ROWS / 4; ++jj) {
            float4 w;
            w.x = lds[(jj * 4 + 0) * WW + x];
            w.y = lds[(jj * 4 + 1) * WW + x];
            w.z = lds[(jj * 4 + 2) * WW + x];
            w.w = lds[(jj * 4 + 3) * WW + x];
            *(float4*)(dst + jj * 4) = w;
        }
    }
}

// ---------------------------------------------------------------------------
// K3: one WAVE per detection box. Lanes stride the y-range of the box reading
// transposed row-prefix columns (contiguous). Also computes+caches det_conf.
// Grid: BB*NN/4 = 1200 blocks of 256 (4 waves).
// ---------------------------------------------------------------------------
__global__ __launch_bounds__(256) void k_det(const float* __restrict__ det_boxes,
                                             const float* __restrict__ logits,
                                             const float* __restrict__ RT,
                                             float* __restrict__ det_conf,
                                             float* __restrict__ detPart) {
    const float CONF_TH = 0.3f;
    const int t = threadIdx.x;
    const int wave = t >> 6, lane = t & 63;
    const int box = blockIdx.x * 4 + wave;        // < 4800 always
    const int b = box / NN;

    // softmax-max confidence (computed redundantly in all lanes)
    const float* lg = logits + (size_t)box * 7;
    float m = lg[0];
    #pragma unroll
    for (int i = 1; i < 7; ++i) m = fmaxf(m, lg[i]);
    float s = 0.f;
    #pragma unroll
    for (int i = 0; i < 7; ++i) s += expf(lg[i] - m);
    float conf = 1.f / s;
    if (lane == 0) det_conf[box] = conf;

    const float* bx = det_boxes + (size_t)box * 4;
    float cx = bx[0], cy = bx[1], w = bx[2], h = bx[3];
    int x1 = (int)floorf((cx - w * 0.5f) * (float)WW);
    int y1 = (int)floorf((cy - h * 0.5f) * (float)HH);
    int x2 = (int)floorf((cx + w * 0.5f) * (float)WW);
    int y2 = (int)floorf((cy + h * 0.5f) * (float)HH);
    x1 = min(max(x1, 0), WW - 1); y1 = min(max(y1, 0), HH - 1);
    x2 = min(max(x2, 0), WW - 1); y2 = min(max(y2, 0), HH - 1);

    float contrib = 0.f;
    if (conf >= CONF_TH && x2 > x1 && y2 > y1) {
        const float* base = RT + (size_t)b * WW * HH;
        const float* c2 = base + (size_t)(x2 - 1) * HH;
        const float* c1 = base + (size_t)max(x1 - 1, 0) * HH;
        const bool has1 = (x1 > 0);
        float acc = 0.f;
        for (int y = y1 + lane; y < y2; y += 64) {
            float v = c2[y];
            if (has1) v -= c1[y];
            acc += v;
        }
        #pragma unroll
        for (int d = 32; d > 0; d >>= 1) acc += __shfl_down(acc, d, 64);
        if (lane == 0) {
            float area = (float)((y2 - y1) * (x2 - x1));
            contrib = relu_f(acc / area) * conf;
        }
    }

    __shared__ float red[4];
    if (lane == 0) red[wave] = contrib;
    __syncthreads();
    if (t == 0) detPart[blockIdx.x] = red[0] + red[1] + red[2] + red[3];
}

// ---------------------------------------------------------------------------
// K4: per-batch plate IoU term + OCR term. One block per batch, 128 threads.
// ---------------------------------------------------------------------------
__global__ void k_plate_ocr(const float* __restrict__ det_boxes,
                            const float* __restrict__ det_conf,
                            const float* __restrict__ plate_boxes,
                            const float* __restrict__ plate_conf,
                            const float* __restrict__ ocr,
                            float* __restrict__ platePart,
                            float* __restrict__ plateCnt,
                            float* __restrict__ ocrPart) {
    const float CONF_TH = 0.3f;
    const float MIN_IOU = 0.5f;
    const float OCR_TH  = 0.7f;
    int b = blockIdx.x;
    int t = threadIdx.x;

    __shared__ float vx1[NN], vy1[NN], vx2[NN], vy2[NN], va[NN], vcf[NN];
    __shared__ int anyv;
    __shared__ float redf[128];
    __shared__ int   redi[128];

    if (t == 0) anyv = 0;
    __syncthreads();

    for (int j = t; j < NN; j += blockDim.x) {
        const float* bx = det_boxes + ((size_t)b * NN + j) * 4;
        float cx = bx[0], cy = bx[1], w = bx[2], h = bx[3];
        float x1 = cx - w * 0.5f, y1 = cy - h * 0.5f;
        float x2 = cx + w * 0.5f, y2 = cy + h * 0.5f;
        vx1[j] = x1; vy1[j] = y1; vx2[j] = x2; vy2[j] = y2;
        va[j] = (x2 - x1) * (y2 - y1);
        float c = det_conf[b * NN + j];
        vcf[j] = c;
        if (c > CONF_TH) atomicOr(&anyv, 1);
    }
    __syncthreads();

    float term = 0.f;
    int   pv   = 0;
    float pcf  = -1.f;
    if (t < PP) {
        const float* bx = plate_boxes + ((size_t)b * PP + t) * 4;
        float cx = bx[0], cy = bx[1], w = bx[2], h = bx[3];
        float px1 = cx - w * 0.5f, py1 = cy - h * 0.5f;
        float px2 = cx + w * 0.5f, py2 = cy + h * 0.5f;
        float a1 = (px2 - px1) * (py2 - py1);
        pcf = plate_conf[b * PP + t];
        pv = (pcf > CONF_TH) ? 1 : 0;
        float max_iou = -1.f;
        for (int j = 0; j < NN; ++j) {
            if (vcf[j] > CONF_TH) {
                float ltx = fmaxf(px1, vx1[j]);
                float lty = fmaxf(py1, vy1[j]);
                float rbx = fminf(px2, vx2[j]);
                float rby = fminf(py2, vy2[j]);
                float iw = fmaxf(rbx - ltx, 0.f);
                float ih = fmaxf(rby - lty, 0.f);
                float inter = iw * ih;
                float uni = a1 + va[j] - inter;
                float iou = inter / (uni + 1e-8f);
                max_iou = fmaxf(max_iou, iou);
            }
        }
        if (pv) term = relu_f(MIN_IOU - max_iou) * pcf;
    }

    redf[t] = term; redi[t] = pv;
    __syncthreads();
    for (int s = 64; s > 0; s >>= 1) {
        if (t < s) { redf[t] += redf[t + s]; redi[t] += redi[t + s]; }
        __syncthreads();
    }
    float termsum = redf[0];
    int   cnt     = redi[0];
    __syncthreads();

    float osum = 0.f;
    if (t < LL) {
        const float* op = ocr + ((size_t)b * LL + t) * 37;
        float m = op[0];
        #pragma unroll
        for (int i = 1; i < 37; ++i) m = fmaxf(m, op[i]);
        osum = m;
    }
    redf[t] = osum;
    __syncthreads();
    for (int s = 64; s > 0; s >>= 1) {
        if (t < s) redf[t] += redf[t + s];
        __syncthreads();
    }
    float avg_ocr = redf[0] / (float)LL;
    __syncthreads();

    redf[t] = (t < PP) ? pcf : -1e30f;
    __syncthreads();
    for (int s = 64; s > 0; s >>= 1) {
        if (t < s) redf[t] = fmaxf(redf[t], redf[t + s]);
        __syncthreads();
    }
    float max_plate = redf[0];

    if (t == 0) {
        platePart[b] = (cnt > 0 && anyv) ? termsum : 0.f;
        plateCnt[b]  = (float)cnt;
        ocrPart[b]   = (avg_ocr > OCR_TH) ? relu_f(avg_ocr - max_plate) : 0.f;
    }
}

// ---------------------------------------------------------------------------
// K5: final deterministic combine, parallel f64 tree over detPart.
// ---------------------------------------------------------------------------
__global__ __launch_bounds__(256) void k_final(const float* __restrict__ detPart, int nDet,
                                               const float* __restrict__ platePart,
                                               const float* __restrict__ plateCnt,
                                               const float* __restrict__ ocrPart,
                                               float* __restrict__ out) {
    __shared__ double red[256];
    int t = threadIdx.x;
    double s = 0.0;
    for (int i = t; i < nDet; i += 256) s += (double)detPart[i];
    red[t] = s;
    __syncthreads();
    for (int k = 128; k > 0; k >>= 1) {
        if (t < k) red[t] += red[t + k];
        __syncthreads();
    }
    if (t == 0) {
        double ps = 0.0, cnt = 0.0, os = 0.0;
        for (int b = 0; b < BB; ++b) {
            ps  += (double)platePart[b];
            cnt += (double)plateCnt[b];
            os  += (double)ocrPart[b];
        }
        float det_seg   = (float)red[0] / (float)(BB * NN);
        float plate_det = (float)ps / fmaxf((float)cnt, 1.f);
        float ocr_plate = (float)os / (float)BB;
        out[0] = 0.1f * det_seg + 0.1f * plate_det + 0.1f * ocr_plate;
    }
}

extern "C" void kernel_launch(void* const* d_in, const int* in_sizes, int n_in,
                              void* d_out, int out_size, void* d_ws, size_t ws_size,
                              hipStream_t stream) {
    const float* det_boxes   = (const float*)d_in[0];
    const float* det_logits  = (const float*)d_in[1];
    const float* seg_masks   = (const float*)d_in[2];
    const float* plate_boxes = (const float*)d_in[3];
    const float* plate_conf  = (const float*)d_in[4];
    const float* ocr_probs   = (const float*)d_in[5];
    float* out = (float*)d_out;

    // workspace layout (floats)
    float* RT        = (float*)d_ws;                     // B*W*H (transposed row-prefix)
    float* det_conf  = RT + (size_t)BB * HH * WW;        // B*N
    float* detPart   = det_conf + BB * NN;               // 1200
    float* platePart = detPart + 1200;                   // 16
    float* plateCnt  = platePart + BB;                   // 16
    float* ocrPart   = plateCnt + BB;                    // 16

    const int nDetBlocks = (BB * NN) / 4;                // 1200 (wave per box)

    k_scan_t<<<BB * (HH / ROWS), 256, 0, stream>>>(seg_masks, RT);
    k_det<<<nDetBlocks, 256, 0, stream>>>(det_boxes, det_logits, RT,
                                          det_conf, detPart);
    k_plate_ocr<<<BB, 128, 0, stream>>>(det_boxes, det_conf, plate_boxes,
                                        plate_conf, ocr_probs,
                                        platePart, plateCnt, ocrPart);
    k_final<<<1, 256, 0, stream>>>(detPart, nDetBlocks, platePart, plateCnt,
                                   ocrPart, out);
}

// Round 3
// 86.640 us; speedup vs baseline: 1.5684x; 1.0289x over previous
//
#include <hip/hip_runtime.h>

#define BB 16
#define NN 300
#define PP 100
#define LL 32
#define HH 768
#define WW 768
#define TSS 64                 // rows per strip
#define NSTRIP (HH / TSS)      // 12
#define KCOLS 16               // columns per block

__device__ __forceinline__ float relu_f(float x) { return fmaxf(x, 0.f); }

// ---------------------------------------------------------------------------
// K1: vertical inclusive prefix I2[b][y][x] = sum_{y'<=y} (seg2 - seg1)[y'][x].
// Block = 12 strips x 16 cols = 192 threads; grid = BB * (WW/KCOLS) = 768
// (exactly 3 blocks/CU). Each thread keeps its strip's 64 d-values in VGPRs
// (fully unrolled, static indices), so seg is read exactly once.
// ---------------------------------------------------------------------------
__global__ __launch_bounds__(192) void k_vprefix(const float* __restrict__ seg,
                                                 float* __restrict__ I2) {
    const int blk = blockIdx.x;
    const int b   = blk / (WW / KCOLS);
    const int x0  = (blk % (WW / KCOLS)) * KCOLS;
    const int t   = threadIdx.x;
    const int c   = t % KCOLS;
    const int s   = t / KCOLS;           // strip 0..11
    const int x   = x0 + c;
    const int y0  = s * TSS;

    const float* p1 = seg + ((size_t)(b * 3 + 1) * HH + y0) * WW + x;
    const float* p2 = seg + ((size_t)(b * 3 + 2) * HH + y0) * WW + x;

    float d[TSS];
    float sum = 0.f;
    #pragma unroll
    for (int i = 0; i < TSS; ++i) {
        d[i] = p2[(size_t)i * WW] - p1[(size_t)i * WW];
        sum += d[i];
    }

    __shared__ float S[NSTRIP][KCOLS];
    S[s][c] = sum;
    __syncthreads();

    float acc = 0.f;
    for (int sp = 0; sp < s; ++sp) acc += S[sp][c];   // exclusive strip offset

    float* o = I2 + ((size_t)b * HH + y0) * WW + x;
    #pragma unroll
    for (int i = 0; i < TSS; ++i) {
        acc += d[i];
        o[(size_t)i * WW] = acc;
    }
}

// ---------------------------------------------------------------------------
// K2: one WAVE per detection box. Lanes stride the x-range reading two
// contiguous rows of I2 (L3-resident). Shuffle reduce.
// Grid: BB*NN/4 = 1200 blocks of 256.
// ---------------------------------------------------------------------------
__global__ __launch_bounds__(256) void k_det(const float* __restrict__ det_boxes,
                                             const float* __restrict__ logits,
                                             const float* __restrict__ I2,
                                             float* __restrict__ detPart) {
    const float CONF_TH = 0.3f;
    const int t = threadIdx.x;
    const int wave = t >> 6, lane = t & 63;
    const int box = blockIdx.x * 4 + wave;        // < 4800 always
    const int b = box / NN;

    const float* lg = logits + (size_t)box * 7;
    float m = lg[0];
    #pragma unroll
    for (int i = 1; i < 7; ++i) m = fmaxf(m, lg[i]);
    float s = 0.f;
    #pragma unroll
    for (int i = 0; i < 7; ++i) s += expf(lg[i] - m);
    float conf = 1.f / s;

    const float* bx = det_boxes + (size_t)box * 4;
    float cx = bx[0], cy = bx[1], w = bx[2], h = bx[3];
    int x1 = (int)floorf((cx - w * 0.5f) * (float)WW);
    int y1 = (int)floorf((cy - h * 0.5f) * (float)HH);
    int x2 = (int)floorf((cx + w * 0.5f) * (float)WW);
    int y2 = (int)floorf((cy + h * 0.5f) * (float)HH);
    x1 = min(max(x1, 0), WW - 1); y1 = min(max(y1, 0), HH - 1);
    x2 = min(max(x2, 0), WW - 1); y2 = min(max(y2, 0), HH - 1);

    float contrib = 0.f;
    if (conf >= CONF_TH && x2 > x1 && y2 > y1) {
        const float* r2 = I2 + ((size_t)b * HH + (y2 - 1)) * WW;
        float acc = 0.f;
        if (y1 > 0) {
            const float* r1 = I2 + ((size_t)b * HH + (y1 - 1)) * WW;
            for (int xx = x1 + lane; xx < x2; xx += 64) acc += r2[xx] - r1[xx];
        } else {
            for (int xx = x1 + lane; xx < x2; xx += 64) acc += r2[xx];
        }
        #pragma unroll
        for (int dd = 32; dd > 0; dd >>= 1) acc += __shfl_down(acc, dd, 64);
        if (lane == 0) {
            float area = (float)((y2 - y1) * (x2 - x1));
            contrib = relu_f(acc / area) * conf;
        }
    }

    __shared__ float red[4];
    if (lane == 0) red[wave] = contrib;
    __syncthreads();
    if (t == 0) detPart[blockIdx.x] = red[0] + red[1] + red[2] + red[3];
}

// ---------------------------------------------------------------------------
// K3: per-batch plate IoU term + OCR term. One block per batch, 128 threads.
// Computes its own det_conf (no dependency on K2's buffer).
// ---------------------------------------------------------------------------
__global__ void k_plate_ocr(const float* __restrict__ det_boxes,
                            const float* __restrict__ logits,
                            const float* __restrict__ plate_boxes,
                            const float* __restrict__ plate_conf,
                            const float* __restrict__ ocr,
                            float* __restrict__ platePart,
                            float* __restrict__ plateCnt,
                            float* __restrict__ ocrPart) {
    const float CONF_TH = 0.3f;
    const float MIN_IOU = 0.5f;
    const float OCR_TH  = 0.7f;
    int b = blockIdx.x;
    int t = threadIdx.x;

    __shared__ float vx1[NN], vy1[NN], vx2[NN], vy2[NN], va[NN], vcf[NN];
    __shared__ int anyv;
    __shared__ float redf[128];
    __shared__ int   redi[128];

    if (t == 0) anyv = 0;
    __syncthreads();

    for (int j = t; j < NN; j += blockDim.x) {
        const float* bx = det_boxes + ((size_t)b * NN + j) * 4;
        float cx = bx[0], cy = bx[1], w = bx[2], h = bx[3];
        float x1 = cx - w * 0.5f, y1 = cy - h * 0.5f;
        float x2 = cx + w * 0.5f, y2 = cy + h * 0.5f;
        vx1[j] = x1; vy1[j] = y1; vx2[j] = x2; vy2[j] = y2;
        va[j] = (x2 - x1) * (y2 - y1);
        const float* lg = logits + ((size_t)b * NN + j) * 7;
        float m = lg[0];
        #pragma unroll
        for (int i = 1; i < 7; ++i) m = fmaxf(m, lg[i]);
        float sum = 0.f;
        #pragma unroll
        for (int i = 0; i < 7; ++i) sum += expf(lg[i] - m);
        float c = 1.f / sum;
        vcf[j] = c;
        if (c > CONF_TH) atomicOr(&anyv, 1);
    }
    __syncthreads();

    float term = 0.f;
    int   pv   = 0;
    float pcf  = -1.f;
    if (t < PP) {
        const float* bx = plate_boxes + ((size_t)b * PP + t) * 4;
        float cx = bx[0], cy = bx[1], w = bx[2], h = bx[3];
        float px1 = cx - w * 0.5f, py1 = cy - h * 0.5f;
        float px2 = cx + w * 0.5f, py2 = cy + h * 0.5f;
        float a1 = (px2 - px1) * (py2 - py1);
        pcf = plate_conf[b * PP + t];
        pv = (pcf > CONF_TH) ? 1 : 0;
        float max_iou = -1.f;
        for (int j = 0; j < NN; ++j) {
            if (vcf[j] > CONF_TH) {
                float ltx = fmaxf(px1, vx1[j]);
                float lty = fmaxf(py1, vy1[j]);
                float rbx = fminf(px2, vx2[j]);
                float rby = fminf(py2, vy2[j]);
                float iw = fmaxf(rbx - ltx, 0.f);
                float ih = fmaxf(rby - lty, 0.f);
                float inter = iw * ih;
                float uni = a1 + va[j] - inter;
                float iou = inter / (uni + 1e-8f);
                max_iou = fmaxf(max_iou, iou);
            }
        }
        if (pv) term = relu_f(MIN_IOU - max_iou) * pcf;
    }

    redf[t] = term; redi[t] = pv;
    __syncthreads();
    for (int s = 64; s > 0; s >>= 1) {
        if (t < s) { redf[t] += redf[t + s]; redi[t] += redi[t + s]; }
        __syncthreads();
    }
    float termsum = redf[0];
    int   cnt     = redi[0];
    __syncthreads();

    float osum = 0.f;
    if (t < LL) {
        const float* op = ocr + ((size_t)b * LL + t) * 37;
        float m = op[0];
        #pragma unroll
        for (int i = 1; i < 37; ++i) m = fmaxf(m, op[i]);
        osum = m;
    }
    redf[t] = osum;
    __syncthreads();
    for (int s = 64; s > 0; s >>= 1) {
        if (t < s) redf[t] += redf[t + s];
        __syncthreads();
    }
    float avg_ocr = redf[0] / (float)LL;
    __syncthreads();

    redf[t] = (t < PP) ? pcf : -1e30f;
    __syncthreads();
    for (int s = 64; s > 0; s >>= 1) {
        if (t < s) redf[t] = fmaxf(redf[t], redf[t + s]);
        __syncthreads();
    }
    float max_plate = redf[0];

    if (t == 0) {
        platePart[b] = (cnt > 0 && anyv) ? termsum : 0.f;
        plateCnt[b]  = (float)cnt;
        ocrPart[b]   = (avg_ocr > OCR_TH) ? relu_f(avg_ocr - max_plate) : 0.f;
    }
}

// ---------------------------------------------------------------------------
// K4: final deterministic combine, parallel f64 tree over detPart.
// ---------------------------------------------------------------------------
__global__ __launch_bounds__(256) void k_final(const float* __restrict__ detPart, int nDet,
                                               const float* __restrict__ platePart,
                                               const float* __restrict__ plateCnt,
                                               const float* __restrict__ ocrPart,
                                               float* __restrict__ out) {
    __shared__ double red[256];
    int t = threadIdx.x;
    double s = 0.0;
    for (int i = t; i < nDet; i += 256) s += (double)detPart[i];
    red[t] = s;
    __syncthreads();
    for (int k = 128; k > 0; k >>= 1) {
        if (t < k) red[t] += red[t + k];
        __syncthreads();
    }
    if (t == 0) {
        double ps = 0.0, cnt = 0.0, os = 0.0;
        for (int b = 0; b < BB; ++b) {
            ps  += (double)platePart[b];
            cnt += (double)plateCnt[b];
            os  += (double)ocrPart[b];
        }
        float det_seg   = (float)red[0] / (float)(BB * NN);
        float plate_det = (float)ps / fmaxf((float)cnt, 1.f);
        float ocr_plate = (float)os / (float)BB;
        out[0] = 0.1f * det_seg + 0.1f * plate_det + 0.1f * ocr_plate;
    }
}

extern "C" void kernel_launch(void* const* d_in, const int* in_sizes, int n_in,
                              void* d_out, int out_size, void* d_ws, size_t ws_size,
                              hipStream_t stream) {
    const float* det_boxes   = (const float*)d_in[0];
    const float* det_logits  = (const float*)d_in[1];
    const float* seg_masks   = (const float*)d_in[2];
    const float* plate_boxes = (const float*)d_in[3];
    const float* plate_conf  = (const float*)d_in[4];
    const float* ocr_probs   = (const float*)d_in[5];
    float* out = (float*)d_out;

    // workspace layout (floats)
    float* I2        = (float*)d_ws;                     // B*H*W vertical prefix
    float* detPart   = I2 + (size_t)BB * HH * WW;        // 1200
    float* platePart = detPart + 1200;                   // 16
    float* plateCnt  = platePart + BB;                   // 16
    float* ocrPart   = plateCnt + BB;                    // 16

    const int nDetBlocks = (BB * NN) / 4;                // 1200 (wave per box)

    k_vprefix<<<BB * (WW / KCOLS), NSTRIP * KCOLS, 0, stream>>>(seg_masks, I2);
    k_det<<<nDetBlocks, 256, 0, stream>>>(det_boxes, det_logits, I2, detPart);
    k_plate_ocr<<<BB, 128, 0, stream>>>(det_boxes, det_logits, plate_boxes,
                                        plate_conf, ocr_probs,
                                        platePart, plateCnt, ocrPart);
    k_final<<<1, 256, 0, stream>>>(detPart, nDetBlocks, platePart, plateCnt,
                                   ocrPart, out);
}